// Round 15
// baseline (186.876 us; speedup 1.0000x reference)
//
#include <hip/hip_runtime.h>
#include <stdint.h>

#define HW 16384
#define NI 64
#define NM 256
#define WORDS 256

// plane padding: stride 136 floats/row (4 guard cols each side, zeroed)
#define PR 136
#define PSZ (26 * PR)   // 3536 floats per plane
// state padding: stride 34 words/row (1 guard word each side, zeroed)
#define SR 34

typedef float v2f __attribute__((ext_vector_type(2)));

// ws layout (~3 MB used)
#define OFF_STATE2 (1u << 20)    // 1 MB state bytes (iter-5 handoff A->B)
#define OFF_PACKED (2u << 20)    // 512 KB bit-packed masks [word][mask]
#define OFF_DIOUT  0x280000u     // 256 KB diou transposed diouT[col][row]
#define OFF_COMPM  0x2C0000u
#define OFF_CNT    0x2C1000u     // 64 counters + done ticket at [64]

// ---------------- fused diou + compm (proven) -------------------------------
__global__ __launch_bounds__(256) void diou_compm_kernel(
    const unsigned long long* __restrict__ packed, const int* __restrict__ labels,
    float* __restrict__ diouT, float* __restrict__ compm) {
    #pragma clang fp contract(off)
    __shared__ unsigned long long colj[WORDS];
    __shared__ float red[NM];
    const int j = blockIdx.x, i = threadIdx.x;
    colj[i] = packed[i * NM + j];
    __syncthreads();
    int inter = 0, si = 0, sj = 0;
    for (int w = 0; w < WORDS; ++w) {
        unsigned long long a = colj[w];
        unsigned long long b = packed[w * NM + i];
        inter += __popcll(a & b);
        sj += __popcll(a);
        si += __popcll(b);
    }
    float d = 0.0f;
    if (j > i && labels[i] == labels[j]) {
        float u = (float)(si + sj - inter);   // exact integers in f32
        d = (float)inter / u;
    }
    diouT[j * NM + i] = d;
    red[i] = d;
    __syncthreads();
    for (int off = 128; off > 0; off >>= 1) {
        if (i < off) red[i] = fmaxf(red[i], red[i + off]);
        __syncthreads();
    }
    if (i == 0) {
        float m = red[0];
        float t = m * m;
        compm[j] = expf(-2.0f * t);
    }
}

// ---------------- CRF: 5 iters/launch (R13 body + pk-f32 + 1 barrier/sweep) -
// 512 blocks = 64 img x 8 tiles of 16 rows; 832 threads = 26-row window x 32
// quads. Planes k=0..3 in LDS (mirror identity, exact; center==3.0f; OOB
// kw==0 exactly). Zero-padded guards: branchless taps (a += lx*0 == a exact).
// Sweep s computes rows [max(0,r0-4+s), min(128,r0+20-s)) — proven bit-exact.
// Accumulate uses float2 ext-vectors -> v_pk_mul/v_pk_add (each component a
// separately-rounded mul then add, same order as reference — bit-identical).
// Early-exit via per-sweep flag chg[s]: one barrier per sweep, no reset race.
template <bool FIRST>
__global__ __launch_bounds__(832, 6) void crf5_kernel(
    const float* __restrict__ feat, const float* __restrict__ scores,
    const float* __restrict__ diouT, const float* __restrict__ compm,
    const float* __restrict__ seg, unsigned long long* __restrict__ packed,
    const float* __restrict__ x, const float* __restrict__ targets,
    unsigned char* __restrict__ state2, float* __restrict__ out,
    int* __restrict__ counters) {
    #pragma clang fp contract(off)
    __shared__ float plane[4 * PSZ];      // 56576 B
    __shared__ uint32_t stw[2][26 * SR];  // 7072 B
    __shared__ int chg[8];                // total 63680 B < 64 KiB
    const int tid = threadIdx.x, bid = blockIdx.x;
    const int img = bid >> 3, r0 = (bid & 7) * 16;
    const int w0 = r0 - 5;
    const int rel = tid >> 5;             // 0..25
    const int q = tid & 31;
    const int xc = q * 4;
    const int y = w0 + rel;
    const bool inimg = (unsigned)y < 128u;

    if (FIRST) {
        // ---- pack (fused; proven ballot body) -----------------------------
        const int wave = tid >> 6, lane = tid & 63;
        const int gw = bid * 13 + wave;          // 6656 waves; 4096 used
        if (gw < 4096) {
            for (int t = 0; t < 16; ++t) {
                int gwi = gw * 16 + t;           // [0, 65536)
                int i = gwi >> 8, w = gwi & 255;
                float v = seg[(size_t)i * HW + w * 64 + lane];
                unsigned long long m = __ballot(v > 0.5f);
                if (lane == 0) packed[w * NM + i] = m;
            }
        }
        if (bid == 0 && tid < NI + 1) counters[tid] = 0;  // [64] = ticket
    } else {
        // ---- coef prologue (blocks 0..255) — plane as scratch -------------
        if (bid < NM) {
            float* red = plane;
            if (tid < NM) {
                float d = diouT[bid * NM + tid];
                float dd = d * d;
                float dec = expf(-2.0f * dd);
                red[tid] = dec / compm[tid];
            }
            __syncthreads();
            for (int off = 128; off > 0; off >>= 1) {
                if (tid < off) red[tid] = fminf(red[tid], red[tid + off]);
                __syncthreads();
            }
            if (tid == 0) out[bid] = scores[bid] * red[0];
            __syncthreads();
        }
    }

    // ---- plane precompute (padded, zero-filled; proven float sequence) -----
    {
        const float* fb = feat + (size_t)img * 3 * HW;
        float c0[4], c1[4], c2[4];
        if (inimg) {
            const int pp = y * 128 + xc;
            float4 cv0 = *(const float4*)&fb[pp];
            float4 cv1 = *(const float4*)&fb[HW + pp];
            float4 cv2 = *(const float4*)&fb[2 * HW + pp];
            c0[0]=cv0.x+10.0f; c0[1]=cv0.y+10.0f; c0[2]=cv0.z+10.0f; c0[3]=cv0.w+10.0f;
            c1[0]=cv1.x+10.0f; c1[1]=cv1.y+10.0f; c1[2]=cv1.z+10.0f; c1[3]=cv1.w+10.0f;
            c2[0]=cv2.x+10.0f; c2[1]=cv2.y+10.0f; c2[2]=cv2.z+10.0f; c2[3]=cv2.w+10.0f;
        }
        #pragma unroll
        for (int k = 0; k < 4; ++k) {
            const int dy = (k < 3) ? -1 : 0;
            const int dx = (k < 3) ? (k - 1) : -1;
            float res[4] = {0.0f, 0.0f, 0.0f, 0.0f};
            if (inimg) {
                const int ny = y + dy;
                if ((unsigned)ny < 128u) {
                    #pragma unroll
                    for (int j = 0; j < 4; ++j) {
                        const int nx = xc + j + dx;
                        if ((unsigned)nx < 128u) {
                            const int qq = ny * 128 + nx;
                            float u0 = fb[qq] + 10.0f;
                            float u1 = fb[HW + qq] + 10.0f;
                            float u2 = fb[2 * HW + qq] + 10.0f;
                            float d0 = u0 - c0[j], d1 = u1 - c1[j], d2 = u2 - c2[j];
                            float ss = d0 * d0;
                            ss = ss + d1 * d1;
                            ss = ss + d2 * d2;
                            float color = (-ss) / 0.5f;
                            float sp = (float)(dy * dy + dx * dx) / 1800.0f;
                            res[j] = 3.0f * expf(color - sp);
                        }
                    }
                }
            }
            *(float4*)&plane[k * PSZ + rel * PR + 4 + xc] =
                make_float4(res[0], res[1], res[2], res[3]);
            if (q == 0)
                *(float4*)&plane[k * PSZ + rel * PR + 0] = make_float4(0, 0, 0, 0);
            if (q == 31)
                *(float4*)&plane[k * PSZ + rel * PR + 132] = make_float4(0, 0, 0, 0);
        }
        // state: A computes iter-0 from x,targets (exact formula); B loads.
        uint32_t st = 0;
        if (inimg) {
            if (FIRST) {
                const size_t gp = (size_t)img * HW + y * 128 + xc;
                const float4 xv = *(const float4*)(x + gp);
                const float4 tv = *(const float4*)(targets + gp);
                float xs[4] = {xv.x, xv.y, xv.z, xv.w};
                float ts[4] = {tv.x, tv.y, tv.z, tv.w};
                #pragma unroll
                for (int j = 0; j < 4; ++j) {
                    float xt = xs[j] * ts[j];
                    int b1 = (xt > 0.5f) ? 1 : 0;
                    int tb = (ts[j] > 0.5f) ? 1 : 0;
                    st |= (uint32_t)(b1 | ((b1 ^ 1) << 1) | (tb << 2)) << (8 * j);
                }
            } else {
                st = ((const uint32_t*)(state2 + (size_t)img * HW + y * 128))[q];
            }
        }
        stw[0][rel * SR + 1 + q] = st;
        if (!inimg) stw[1][rel * SR + 1 + q] = 0;
        if (q == 0)  { stw[0][rel * SR + 0]  = 0; stw[1][rel * SR + 0]  = 0; }
        if (q == 31) { stw[0][rel * SR + 33] = 0; stw[1][rel * SR + 33] = 0; }
        if (tid < 8) chg[tid] = 0;   // per-sweep early-exit flags
    }
    __syncthreads();

    // ---- 5 sweeps: branchless taps, pk-f32 accumulate, 1 barrier/sweep -----
    const float l45 = 0.7985076962177716f;  // -log(0.45f)
    const float l55 = 0.5978370007556204f;  // -log(0.55f)
    const bool compute = inimg && (y >= r0 - 4) && (y < r0 + 20);
    const int lane = tid & 63;
    const int rbase = rel * PR + 4 + xc;
    const int sbase = rel * SR + 1 + q;
    int cur = 0;
    for (int s = 0; s < 5; ++s) {
        const int lo = (r0 - 4 + s < 0) ? 0 : r0 - 4 + s;
        const int hi = (r0 + 20 - s > 128) ? 128 : r0 + 20 - s;
        const bool act = compute && (y >= lo) && (y < hi);
        bool changed = false;
        if (act) {
            const uint32_t* sw = &stw[cur][0];
            // per-row (lx1,lx0) pair table from 9 padded word reads
            v2f lx01[3][6];
            uint32_t wcen = 0;
            #pragma unroll
            for (int r = 0; r < 3; ++r) {
                const int base = sbase + (r - 1) * SR;
                const uint32_t wm = sw[base - 1];
                const uint32_t wc = sw[base];
                const uint32_t wp = sw[base + 1];
                if (r == 1) wcen = wc;
                unsigned char b[6];
                b[0] = wm >> 24;
                b[1] = wc & 0xff; b[2] = (wc >> 8) & 0xff;
                b[3] = (wc >> 16) & 0xff; b[4] = wc >> 24;
                b[5] = wp & 0xff;
                #pragma unroll
                for (int m = 0; m < 6; ++m) {
                    lx01[r][m].x = (b[m] & 1) ? l55 : l45;
                    lx01[r][m].y = (b[m] & 2) ? l55 : l45;
                }
            }
            // kw gather: 7 x b128 + 3 scalars via mirror identity
            float4 p0a = *(const float4*)&plane[0 * PSZ + rbase];
            float4 p1a = *(const float4*)&plane[1 * PSZ + rbase];
            float4 p2a = *(const float4*)&plane[2 * PSZ + rbase];
            float4 p3a = *(const float4*)&plane[3 * PSZ + rbase];
            float4 p0b = *(const float4*)&plane[0 * PSZ + rbase + PR];
            float4 p1b = *(const float4*)&plane[1 * PSZ + rbase + PR];
            float4 p2b = *(const float4*)&plane[2 * PSZ + rbase + PR];
            float s5 = plane[3 * PSZ + rbase + 4];
            float s6 = plane[2 * PSZ + rbase + PR - 1];
            float s8 = plane[0 * PSZ + rbase + PR + 4];
            const float kw[9][4] = {
                {p0a.x, p0a.y, p0a.z, p0a.w},
                {p1a.x, p1a.y, p1a.z, p1a.w},
                {p2a.x, p2a.y, p2a.z, p2a.w},
                {p3a.x, p3a.y, p3a.z, p3a.w},
                {3.0f, 3.0f, 3.0f, 3.0f},
                {p3a.y, p3a.z, p3a.w, s5},
                {s6, p2b.x, p2b.y, p2b.z},
                {p1b.x, p1b.y, p1b.z, p1b.w},
                {p0b.y, p0b.z, p0b.w, s8}};
            // packed accumulate: .x = lx1 chain, .y = lx0 chain (same order)
            v2f a01[4];
            #pragma unroll
            for (int j = 0; j < 4; ++j) a01[j] = (v2f){0.0f, 0.0f};
            #pragma unroll
            for (int k = 0; k < 9; ++k) {
                const int r = k / 3, m0 = k % 3;
                #pragma unroll
                for (int j = 0; j < 4; ++j) {
                    const float kwv = kw[k][j];
                    const v2f t = lx01[r][j + m0] * (v2f){kwv, kwv};  // pk_mul
                    a01[j] = a01[j] + t;                              // pk_add
                }
            }
            // epilogue (proven exact sequence)
            uint32_t ow = 0;
            #pragma unroll
            for (int j = 0; j < 4; ++j) {
                const unsigned char sc = (wcen >> (8 * j)) & 0xffu;
                const float tval = (sc & 4) ? 1.0f : 0.0f;
                const float e1 = expf(-a01[j].x);
                const float e0 = expf(-a01[j].y);
                const float m1 = e1 * tval;
                const float f1 = m1 + 1e-6f;
                const float f0 = e0 + 1e-6f;
                const float den = f0 + f1;
                const float r1 = f1 / den;
                const float r0v = f0 / den;
                const int s1 = (r1 > 0.5f) ? 1 : 0;
                const int s0 = (r0v > 0.5f) ? 1 : 0;
                ow |= (uint32_t)(s1 | (s0 << 1) | (sc & 4)) << (8 * j);
            }
            stw[cur ^ 1][sbase] = ow;
            changed = (ow != wcen);
        }
        unsigned long long bal = __ballot(changed);
        if (lane == 0 && bal) atomicOr(&chg[s], 1);
        __syncthreads();                 // orders stw writes + chg for all
        if (chg[s] == 0) break;          // fixed point: later sweeps identical
        cur ^= 1;
    }

    // ---- emission from stw[cur] --------------------------------------------
    int cnt = 0;
    if (inimg && y >= r0 && y < r0 + 16) {
        const uint32_t w = stw[cur][sbase];
        if (FIRST) {
            ((uint32_t*)(state2 + (size_t)img * HW))[y * 32 + q] = w;
        } else {
            float* om = out + NM + (size_t)img * HW;
            *(float4*)(om + y * 128 + xc) =
                make_float4((float)(w & 1), (float)((w >> 8) & 1),
                            (float)((w >> 16) & 1), (float)((w >> 24) & 1));
            cnt = __popc(w & 0x01010101u);
        }
    }

    // ---- phase B tail: counts + valid (proven ticket) ----------------------
    if (!FIRST) {
        __syncthreads();   // before plane reuse as cred
        int* cred = (int*)plane;
        cred[tid] = cnt;
        if (tid < 192) cred[832 + tid] = 0;   // pad to 1024
        __syncthreads();
        for (int off = 512; off > 0; off >>= 1) {
            if (tid < off) cred[tid] += cred[tid + off];
            __syncthreads();
        }
        int* flag = (int*)&stw[0][0];
        if (tid == 0) {
            atomicAdd(&counters[img], cred[0]);
            __threadfence();
            int old = atomicAdd(&counters[NI], 1);
            flag[0] = (old == 511) ? 1 : 0;
        }
        __syncthreads();
        if (flag[0] && tid < NI) {
            int c = atomicAdd(&counters[tid], 0);
            // 16384*0.05 = 819.2, 16384*0.95 = 15564.8; counts are integers
            out[NM + (size_t)NI * HW + tid] = (c >= 820 && c <= 15564) ? 1.0f : 0.0f;
        }
    }
}

extern "C" void kernel_launch(void* const* d_in, const int* in_sizes, int n_in,
                              void* d_out, int out_size, void* d_ws, size_t ws_size,
                              hipStream_t stream) {
    const float* seg = (const float*)d_in[0];
    const float* cate_scores = (const float*)d_in[1];
    const float* feat = (const float*)d_in[2];
    const float* x = (const float*)d_in[3];
    const float* targets = (const float*)d_in[4];
    const int* labels = (const int*)d_in[5];
    float* out = (float*)d_out;
    char* ws = (char*)d_ws;

    unsigned char* state2 = (unsigned char*)(ws + OFF_STATE2);
    unsigned long long* packed = (unsigned long long*)(ws + OFF_PACKED);
    float* diouT = (float*)(ws + OFF_DIOUT);
    float* compm = (float*)(ws + OFF_COMPM);
    int* counters = (int*)(ws + OFF_CNT);

    // Node 1: CRF iters 1-5 + mask-pack + iter-0 state + counter zero
    crf5_kernel<true><<<512, 832, 0, stream>>>(feat, cate_scores, diouT, compm,
                                               seg, packed, x, targets, state2,
                                               out, counters);
    // Node 2: NMS diou + compm (needs packed from node 1)
    diou_compm_kernel<<<NM, 256, 0, stream>>>(packed, labels, diouT, compm);
    // Node 3: coef + CRF iters 6-10 + masks/counts/valid
    crf5_kernel<false><<<512, 832, 0, stream>>>(feat, cate_scores, diouT, compm,
                                                seg, packed, x, targets, state2,
                                                out, counters);
}